// Round 6
// baseline (386.281 us; speedup 1.0000x reference)
//
#include <hip/hip_runtime.h>

typedef unsigned short u16;
typedef unsigned int u32;
typedef __bf16 bf16x8 __attribute__((ext_vector_type(8)));
typedef float f32x4 __attribute__((ext_vector_type(4)));

#define B_  4
#define T_  2048
#define C_  1024
#define NH_ 16
#define D_  64
#define M_  (B_*T_)          // 8192
#define N_QKV (3*C_)         // 3072

#define ATTN_WAVES 3072      // 12 per CU (3 per SIMD)
#define ATTN_ITEMS 4096      // 64 bh x 64 q-tiles of 32 rows

// async global->LDS, 16B per lane. LDS dest = wave-uniform base + lane*16
__device__ __forceinline__ void async_copy16(void* lds, const void* gptr) {
  __builtin_amdgcn_global_load_lds(
      (const __attribute__((address_space(1))) u32*)gptr,
      (__attribute__((address_space(3))) u32*)(u32)(uintptr_t)lds,
      16, 0, 0);
}

// RNE float -> bf16 bits
__device__ __forceinline__ u16 f2bf(float f) {
  union { float f; unsigned u; } c; c.f = f;
  unsigned u = c.u;
  unsigned r = (u + 0x7fffu + ((u >> 16) & 1u)) >> 16;
  return (u16)r;
}

// ---------------- elementwise fp32 -> bf16 ----------------
__global__ __launch_bounds__(256) void conv_bf16(const float* __restrict__ in,
                                                 u16* __restrict__ out, int n) {
  int i = (blockIdx.x * 256 + threadIdx.x) * 4;
  if (i < n) {
    float4 f = *reinterpret_cast<const float4*>(in + i);
    u16 o[4] = { f2bf(f.x), f2bf(f.y), f2bf(f.z), f2bf(f.w) };
    *reinterpret_cast<uint2*>(out + i) = *reinterpret_cast<uint2*>(o);
  }
}

// ---------------- transpose fp32 [K][N] -> bf16 [N][K] ----------------
__global__ __launch_bounds__(256) void transpose_bf16(const float* __restrict__ in,
                                                      u16* __restrict__ out,
                                                      int K, int N) {
  __shared__ float tile[32][33];
  int bi = blockIdx.y;           // K/32
  int bj = blockIdx.x;           // N/32
  int tx = threadIdx.x & 31;
  int ty = threadIdx.x >> 5;     // 0..7
#pragma unroll
  for (int i = 0; i < 4; ++i) {
    int row = ty + i * 8;
    tile[row][tx] = in[(bi * 32 + row) * N + bj * 32 + tx];
  }
  __syncthreads();
#pragma unroll
  for (int i = 0; i < 4; ++i) {
    int row = ty + i * 8;
    out[(bj * 32 + row) * K + bi * 32 + tx] = f2bf(tile[tx][row]);
  }
}

// ---------------- QKV GEMM: BK=64, global_load_lds staging, 32 MFMA/barrier ----------------
// 128x128 tile. As/Bs flat [128][64] u16 (unpadded, lane-contiguous chunks).
// q stored pre-scaled by 1/sqrt(D)*log2(e); k with bias; v transposed [b,h,d,t].
__global__ __launch_bounds__(256) void gemm_qkv(const u16* __restrict__ A,
                                                const u16* __restrict__ Bt,
                                                const float* __restrict__ b_attn,
                                                const float* __restrict__ bQ,
                                                const float* __restrict__ bK,
                                                u16* __restrict__ qo,
                                                u16* __restrict__ ko,
                                                u16* __restrict__ vo,
                                                unsigned* __restrict__ ctr) {
  const int K = C_;
  int bm = blockIdx.y, bn = blockIdx.x;
  int tid = threadIdx.x;
  if (tid == 0 && bm == 0 && bn == 0) *ctr = ATTN_WAVES;
  int wid = tid >> 6, lane = tid & 63;
  int lm = lane & 15, lq = lane >> 4;
  int wm = (wid >> 1) * 64, wn = (wid & 1) * 64;

  __shared__ u16 As[128 * 64];
  __shared__ u16 Bs[128 * 64];

  f32x4 acc[4][4];
#pragma unroll
  for (int i = 0; i < 4; ++i)
#pragma unroll
    for (int j = 0; j < 4; ++j) acc[i][j] = (f32x4){0.f, 0.f, 0.f, 0.f};

  const u16* Ab = A + (bm * 128) * K;
  const u16* Bb = Bt + (bn * 128) * K;
  // chunk c (0..15) = rows 8c..8c+7 (128B/row); lane i -> row 8c+(i>>3), col (i&7)*8
  int crow = lane >> 3;
  int ccol = (lane & 7) * 8;

  for (int k0 = 0; k0 < K; k0 += 64) {
    __syncthreads();               // protect previous iteration's ds_reads
#pragma unroll
    for (int j = 0; j < 4; ++j) {
      int c = wid * 4 + j;
      int row = c * 8 + crow;
      async_copy16(&As[c * 512], Ab + row * K + k0 + ccol);
      async_copy16(&Bs[c * 512], Bb + row * K + k0 + ccol);
    }
    __syncthreads();               // drains vmcnt (global_load_lds) per wave
#pragma unroll
    for (int s = 0; s < 2; ++s) {
      bf16x8 af[4], bf[4];
#pragma unroll
      for (int mt = 0; mt < 4; ++mt)
        af[mt] = *reinterpret_cast<const bf16x8*>(&As[(wm + mt * 16 + lm) * 64 + s * 32 + lq * 8]);
#pragma unroll
      for (int nt = 0; nt < 4; ++nt)
        bf[nt] = *reinterpret_cast<const bf16x8*>(&Bs[(wn + nt * 16 + lm) * 64 + s * 32 + lq * 8]);
#pragma unroll
      for (int mt = 0; mt < 4; ++mt)
#pragma unroll
        for (int nt = 0; nt < 4; ++nt)
          acc[mt][nt] = __builtin_amdgcn_mfma_f32_16x16x32_bf16(af[mt], bf[nt], acc[mt][nt], 0, 0, 0);
    }
  }

  const float qscale = 0.18033688011112042f;  // 1/sqrt(64) * log2(e)
  // epilogue: C/D layout col=lane&15, row=(lane>>4)*4+reg  [verified m89/m91]
#pragma unroll
  for (int mt = 0; mt < 4; ++mt) {
#pragma unroll
    for (int nt = 0; nt < 4; ++nt) {
#pragma unroll
      for (int r = 0; r < 4; ++r) {
        int m = bm * 128 + wm + mt * 16 + lq * 4 + r;
        int n = bn * 128 + wn + nt * 16 + lm;
        float val = acc[mt][nt][r] + b_attn[n];
        int sel = n >> 10;
        int c = n & 1023;          // h*64+d
        int h = c >> 6;
        int d = c & 63;
        int b = m >> 11;
        int t = m & 2047;
        if (sel == 0)      qo[(((b * NH_ + h) * T_) + t) * D_ + d] = f2bf((val + bQ[c]) * qscale);
        else if (sel == 1) ko[(((b * NH_ + h) * T_) + t) * D_ + d] = f2bf(val + bK[c]);
        else               vo[(((b * NH_ + h) * D_) + d) * T_ + t] = f2bf(val);  // transposed
      }
    }
  }
}

// ---------------- Flash attention: persistent waves + K-frag register pipeline ----------------
// 3072 single-wave blocks. Work item idx: qt = 63-(idx>>6) (longest first),
// bh = idx&63; steal via *ctr. S^T = K Q^T (q in lane dim). K fragments are
// double-buffered in registers: next tile's loads issue before this tile's
// compute, so their vmcnt wait lands a full iteration later (latency hidden).
__global__ __launch_bounds__(64) void attn_kernel(const u16* __restrict__ q,
                                                  const u16* __restrict__ k,
                                                  const u16* __restrict__ vt,
                                                  u16* __restrict__ y,
                                                  unsigned* __restrict__ ctr) {
  int lane = threadIdx.x;
  int lm = lane & 15, lq = lane >> 4;

  __shared__ u16 Ps[2][16][72];    // [q-subtile][q-row][local key], row stride 72

  int idx = blockIdx.x;
  while (idx < ATTN_ITEMS) {
    int qt = 63 - (idx >> 6);
    int bh = idx & 63;
    int b = bh >> 4, h = bh & 15;

    const u16* qb = q + ((size_t)bh * T_ + qt * 32) * D_;
    const u16* kb = k + (size_t)bh * T_ * D_;
    const u16* vb = vt + (size_t)bh * D_ * T_;   // [d][t]

    // Q as B-operand: lane n=q=lm, k=d=lq*8+j
    bf16x8 bq[2][2];
#pragma unroll
    for (int qt2 = 0; qt2 < 2; ++qt2) {
      const u16* qp = qb + (qt2 * 16 + lm) * D_ + lq * 8;
      bq[qt2][0] = *reinterpret_cast<const bf16x8*>(qp);
      bq[qt2][1] = *reinterpret_cast<const bf16x8*>(qp + 32);
    }

    f32x4 o[4][2];                 // O^T tiles: [d-tile][q-subtile]
#pragma unroll
    for (int dt = 0; dt < 4; ++dt)
#pragma unroll
      for (int qt2 = 0; qt2 < 2; ++qt2) o[dt][qt2] = (f32x4){0.f, 0.f, 0.f, 0.f};
    float mprev[2] = {-1e30f, -1e30f}, lsum[2] = {0.f, 0.f};

    const int klast = qt >> 1;

    // K-fragment loader: lane m=key=lm, k=d
    auto ldk = [&](bf16x8 (&kf)[4][2], int kbi) {
#pragma unroll
      for (int nt = 0; nt < 4; ++nt) {
        const u16* kp = kb + (size_t)(kbi * 64 + nt * 16 + lm) * D_ + lq * 8;
        kf[nt][0] = *reinterpret_cast<const bf16x8*>(kp);
        kf[nt][1] = *reinterpret_cast<const bf16x8*>(kp + 32);
      }
    };

    // one 64-key iteration using the given (already-loaded) K fragments
    auto body = [&](bf16x8 (&kf)[4][2], int kbi) {
      // S^T[key][q] (exp2 domain: q pre-scaled)
      f32x4 s[4][2];
#pragma unroll
      for (int kt = 0; kt < 4; ++kt)
#pragma unroll
        for (int qt2 = 0; qt2 < 2; ++qt2) {
          f32x4 z = (f32x4){0.f, 0.f, 0.f, 0.f};
          z = __builtin_amdgcn_mfma_f32_16x16x32_bf16(kf[kt][0], bq[qt2][0], z, 0, 0, 0);
          z = __builtin_amdgcn_mfma_f32_16x16x32_bf16(kf[kt][1], bq[qt2][1], z, 0, 0, 0);
          s[kt][qt2] = z;
        }

      // V^T fragments: issued here so softmax latency covers them
      bf16x8 vf[4][2];
#pragma unroll
      for (int dt = 0; dt < 4; ++dt) {
        const u16* vp = vb + (size_t)(dt * 16 + lm) * T_ + kbi * 64 + lq * 8;
        vf[dt][0] = *reinterpret_cast<const bf16x8*>(vp);
        vf[dt][1] = *reinterpret_cast<const bf16x8*>(vp + 32);
      }

      bool maskt = (kbi == klast);
#pragma unroll
      for (int qt2 = 0; qt2 < 2; ++qt2) {
        int qg = qt * 32 + qt2 * 16 + lm;
        float mval = -1e30f;
        if (maskt) {
#pragma unroll
          for (int kt = 0; kt < 4; ++kt)
#pragma unroll
            for (int r = 0; r < 4; ++r) {
              int key = kbi * 64 + kt * 16 + lq * 4 + r;
              float sv = (key > qg) ? -1e30f : s[kt][qt2][r];
              s[kt][qt2][r] = sv;
              mval = fmaxf(mval, sv);
            }
        } else {
#pragma unroll
          for (int kt = 0; kt < 4; ++kt)
#pragma unroll
            for (int r = 0; r < 4; ++r) mval = fmaxf(mval, s[kt][qt2][r]);
        }
        mval = fmaxf(mval, __shfl_xor(mval, 16));
        mval = fmaxf(mval, __shfl_xor(mval, 32));
        float mold = mprev[qt2];
        float mnew = fmaxf(mold, mval);
        unsigned long long upd = __ballot(mval > mold);
        if (upd) {                       // wave-uniform branch
          float alpha = __builtin_exp2f(mold - mnew);
          lsum[qt2] *= alpha;
#pragma unroll
          for (int dt = 0; dt < 4; ++dt) o[dt][qt2] *= alpha;
          mprev[qt2] = mnew;
        }
        float rs = 0.f;
#pragma unroll
        for (int kt = 0; kt < 4; ++kt) {
          unsigned pu[4];
#pragma unroll
          for (int r = 0; r < 4; ++r) {
            float p = __builtin_exp2f(s[kt][qt2][r] - mnew);
            rs += p;
            union { float f; unsigned u; } cc; cc.f = p;
            pu[r] = cc.u;
          }
          // truncating bf16 pack: 2 keys/u32
          unsigned w0 = (pu[0] >> 16) | (pu[1] & 0xffff0000u);
          unsigned w1 = (pu[2] >> 16) | (pu[3] & 0xffff0000u);
          unsigned long long wv = ((unsigned long long)w1 << 32) | w0;
          *reinterpret_cast<unsigned long long*>(&Ps[qt2][lm][kt * 16 + lq * 4]) = wv;
        }
        rs += __shfl_xor(rs, 16);
        rs += __shfl_xor(rs, 32);
        lsum[qt2] += rs;
      }

      // PV: O^T += V^T P^T  (per-wave LDS readback, no barrier)
#pragma unroll
      for (int qt2 = 0; qt2 < 2; ++qt2) {
        bf16x8 p0 = *reinterpret_cast<const bf16x8*>(&Ps[qt2][lm][lq * 8]);
        bf16x8 p1 = *reinterpret_cast<const bf16x8*>(&Ps[qt2][lm][32 + lq * 8]);
#pragma unroll
        for (int dt = 0; dt < 4; ++dt) {
          o[dt][qt2] = __builtin_amdgcn_mfma_f32_16x16x32_bf16(vf[dt][0], p0, o[dt][qt2], 0, 0, 0);
          o[dt][qt2] = __builtin_amdgcn_mfma_f32_16x16x32_bf16(vf[dt][1], p1, o[dt][qt2], 0, 0, 0);
        }
      }
    };

    // ping-pong pipelined K-loop (buffers are distinct named arrays -> regs)
    bf16x8 kfA[4][2], kfB[4][2];
    ldk(kfA, 0);
    for (int kbi = 0; kbi <= klast; kbi += 2) {
      ldk(kfB, (kbi + 1 <= klast) ? kbi + 1 : klast);   // clamp: redundant but in-bounds
      body(kfA, kbi);
      if (kbi + 1 > klast) break;
      ldk(kfA, (kbi + 2 <= klast) ? kbi + 2 : klast);
      body(kfB, kbi + 1);
    }

    // write y[b][t=q][h][d]; O^T C-layout: col=q=lm, row=d=dt*16+lq*4+r -> 8B stores
#pragma unroll
    for (int qt2 = 0; qt2 < 2; ++qt2) {
      float inv = 1.f / lsum[qt2];
      int qg = qt * 32 + qt2 * 16 + lm;
#pragma unroll
      for (int dt = 0; dt < 4; ++dt) {
        u16 w[4];
#pragma unroll
        for (int r = 0; r < 4; ++r) w[r] = f2bf(o[dt][qt2][r] * inv);
        int d = dt * 16 + lq * 4;
        *reinterpret_cast<uint2*>(&y[((size_t)(b * T_ + qg) * NH_ + h) * D_ + d]) =
            *reinterpret_cast<uint2*>(w);
      }
    }

    // steal next item
    unsigned nv = 0;
    if (lane == 0) nv = atomicAdd(ctr, 1u);
    idx = __shfl((int)nv, 0);
  }
}

// ---------------- Proj GEMM: BK=64 staging, y[M,K] x WpT[N,K] + b_proj -> fp32 ----------------
__global__ __launch_bounds__(256) void gemm_proj(const u16* __restrict__ A,
                                                 const u16* __restrict__ Bt,
                                                 const float* __restrict__ b_proj,
                                                 float* __restrict__ out) {
  const int K = C_, N = C_;
  int bm = blockIdx.y, bn = blockIdx.x;
  int tid = threadIdx.x;
  int wid = tid >> 6, lane = tid & 63;
  int lm = lane & 15, lq = lane >> 4;
  int wm = (wid >> 1) * 64, wn = (wid & 1) * 64;

  __shared__ u16 As[128 * 64];
  __shared__ u16 Bs[128 * 64];

  f32x4 acc[4][4];
#pragma unroll
  for (int i = 0; i < 4; ++i)
#pragma unroll
    for (int j = 0; j < 4; ++j) acc[i][j] = (f32x4){0.f, 0.f, 0.f, 0.f};

  const u16* Ab = A + (bm * 128) * K;
  const u16* Bb = Bt + (bn * 128) * K;
  int crow = lane >> 3;
  int ccol = (lane & 7) * 8;

  for (int k0 = 0; k0 < K; k0 += 64) {
    __syncthreads();
#pragma unroll
    for (int j = 0; j < 4; ++j) {
      int c = wid * 4 + j;
      int row = c * 8 + crow;
      async_copy16(&As[c * 512], Ab + row * K + k0 + ccol);
      async_copy16(&Bs[c * 512], Bb + row * K + k0 + ccol);
    }
    __syncthreads();
#pragma unroll
    for (int s = 0; s < 2; ++s) {
      bf16x8 af[4], bf[4];
#pragma unroll
      for (int mt = 0; mt < 4; ++mt)
        af[mt] = *reinterpret_cast<const bf16x8*>(&As[(wm + mt * 16 + lm) * 64 + s * 32 + lq * 8]);
#pragma unroll
      for (int nt = 0; nt < 4; ++nt)
        bf[nt] = *reinterpret_cast<const bf16x8*>(&Bs[(wn + nt * 16 + lm) * 64 + s * 32 + lq * 8]);
#pragma unroll
      for (int mt = 0; mt < 4; ++mt)
#pragma unroll
        for (int nt = 0; nt < 4; ++nt)
          acc[mt][nt] = __builtin_amdgcn_mfma_f32_16x16x32_bf16(af[mt], bf[nt], acc[mt][nt], 0, 0, 0);
    }
  }

#pragma unroll
  for (int mt = 0; mt < 4; ++mt) {
#pragma unroll
    for (int nt = 0; nt < 4; ++nt) {
#pragma unroll
      for (int r = 0; r < 4; ++r) {
        int m = bm * 128 + wm + mt * 16 + lq * 4 + r;
        int n = bn * 128 + wn + nt * 16 + lm;
        out[m * N + n] = acc[mt][nt][r] + b_proj[n];
      }
    }
  }
}

extern "C" void kernel_launch(void* const* d_in, const int* in_sizes, int n_in,
                              void* d_out, int out_size, void* d_ws, size_t ws_size,
                              hipStream_t stream) {
  const float* x      = (const float*)d_in[0];
  const float* W_attn = (const float*)d_in[1];
  const float* b_attn = (const float*)d_in[2];
  const float* bQ     = (const float*)d_in[3];
  const float* bK     = (const float*)d_in[4];
  const float* W_proj = (const float*)d_in[5];
  const float* b_proj = (const float*)d_in[6];
  float* out = (float*)d_out;

  char* ws = (char*)d_ws;
  u16* xb  = (u16*)(ws);                              // [8192][1024]      16 MB
  u16* WaT = (u16*)(ws + 16777216);                   // [3072][1024]       6 MB
  u16* WpT = (u16*)(ws + 23068672);                   // [1024][1024]       2 MB
  u16* qw  = (u16*)(ws + 25165824);                   // [B,NH,T,D] scaled 16 MB
  u16* kw  = (u16*)(ws + 41943040);                   // [B,NH,T,D]        16 MB
  u16* vw  = (u16*)(ws + 58720256);                   // [B,NH,D,T] (V^T)  16 MB
  u16* yw  = (u16*)(ws + 75497472);                   // [8192][1024]      16 MB
  unsigned* ctr = (unsigned*)(ws + 92274688);         // work-steal counter

  conv_bf16<<<M_ * C_ / (4 * 256), 256, 0, stream>>>(x, xb, M_ * C_);
  {
    dim3 g(N_QKV / 32, C_ / 32);
    transpose_bf16<<<g, 256, 0, stream>>>(W_attn, WaT, C_, N_QKV);
  }
  {
    dim3 g(C_ / 32, C_ / 32);
    transpose_bf16<<<g, 256, 0, stream>>>(W_proj, WpT, C_, C_);
  }
  {
    dim3 g(N_QKV / 128, M_ / 128);  // (24, 64)
    gemm_qkv<<<g, 256, 0, stream>>>(xb, WaT, b_attn, bQ, bK, qw, kw, vw, ctr);
  }
  attn_kernel<<<ATTN_WAVES, 64, 0, stream>>>(qw, kw, vw, yw, ctr);
  {
    dim3 g(C_ / 128, M_ / 128);     // (8, 64)
    gemm_proj<<<g, 256, 0, stream>>>(yw, WpT, b_proj, out);
  }
}

// Round 7
// 352.838 us; speedup vs baseline: 1.0948x; 1.0948x over previous
//
#include <hip/hip_runtime.h>

typedef unsigned short u16;
typedef unsigned int u32;
typedef __bf16 bf16x8 __attribute__((ext_vector_type(8)));
typedef float f32x4 __attribute__((ext_vector_type(4)));

#define B_  4
#define T_  2048
#define C_  1024
#define NH_ 16
#define D_  64
#define M_  (B_*T_)          // 8192
#define N_QKV (3*C_)         // 3072

#define ATTN_WAVES 1280      // 5 blocks/CU (LDS-limited), persistent
#define ATTN_ITEMS 4096      // 64 bh x 64 q-tiles of 32 rows

// s_waitcnt imm (gfx9 encoding): lgkm=15 (no wait), exp=7 (no wait), vmcnt in [3:0]|[15:14]
#define WAIT_VM8() __builtin_amdgcn_s_waitcnt(0x0F78)   // vmcnt(8)

// async global->LDS, 16B per lane. LDS dest = wave-uniform base + lane*16
__device__ __forceinline__ void async_copy16(void* lds, const void* gptr) {
  __builtin_amdgcn_global_load_lds(
      (const __attribute__((address_space(1))) u32*)gptr,
      (__attribute__((address_space(3))) u32*)(u32)(uintptr_t)lds,
      16, 0, 0);
}

// RNE float -> bf16 bits
__device__ __forceinline__ u16 f2bf(float f) {
  union { float f; unsigned u; } c; c.f = f;
  unsigned u = c.u;
  unsigned r = (u + 0x7fffu + ((u >> 16) & 1u)) >> 16;
  return (u16)r;
}

// ---------------- elementwise fp32 -> bf16 ----------------
__global__ __launch_bounds__(256) void conv_bf16(const float* __restrict__ in,
                                                 u16* __restrict__ out, int n) {
  int i = (blockIdx.x * 256 + threadIdx.x) * 4;
  if (i < n) {
    float4 f = *reinterpret_cast<const float4*>(in + i);
    u16 o[4] = { f2bf(f.x), f2bf(f.y), f2bf(f.z), f2bf(f.w) };
    *reinterpret_cast<uint2*>(out + i) = *reinterpret_cast<uint2*>(o);
  }
}

// ---------------- transpose fp32 [K][N] -> bf16 [N][K] ----------------
__global__ __launch_bounds__(256) void transpose_bf16(const float* __restrict__ in,
                                                      u16* __restrict__ out,
                                                      int K, int N) {
  __shared__ float tile[32][33];
  int bi = blockIdx.y;
  int bj = blockIdx.x;
  int tx = threadIdx.x & 31;
  int ty = threadIdx.x >> 5;
#pragma unroll
  for (int i = 0; i < 4; ++i) {
    int row = ty + i * 8;
    tile[row][tx] = in[(bi * 32 + row) * N + bj * 32 + tx];
  }
  __syncthreads();
#pragma unroll
  for (int i = 0; i < 4; ++i) {
    int row = ty + i * 8;
    out[(bj * 32 + row) * K + bi * 32 + tx] = f2bf(tile[tx][row]);
  }
}

// ---------------- QKV GEMM (R5 BK=32 m97 structure) ----------------
__global__ __launch_bounds__(256) void gemm_qkv(const u16* __restrict__ A,
                                                const u16* __restrict__ Bt,
                                                const float* __restrict__ b_attn,
                                                const float* __restrict__ bQ,
                                                const float* __restrict__ bK,
                                                u16* __restrict__ qo,
                                                u16* __restrict__ ko,
                                                u16* __restrict__ vo,
                                                unsigned* __restrict__ ctr) {
  const int K = C_;
  int bm = blockIdx.y, bn = blockIdx.x;
  int tid = threadIdx.x;
  if (tid == 0 && bm == 0 && bn == 0) *ctr = ATTN_WAVES;
  int wid = tid >> 6, lane = tid & 63;
  int lm = lane & 15, lq = lane >> 4;
  int wm = (wid >> 1) * 64, wn = (wid & 1) * 64;

  __shared__ u16 As[128 * 32];
  __shared__ u16 Bs[128 * 32];

  f32x4 acc[4][4];
#pragma unroll
  for (int i = 0; i < 4; ++i)
#pragma unroll
    for (int j = 0; j < 4; ++j) acc[i][j] = (f32x4){0.f, 0.f, 0.f, 0.f};

  const u16* Ab = A + (bm * 128) * K;
  const u16* Bb = Bt + (bn * 128) * K;
  int srow = lane >> 2;
  int scol = (lane & 3) * 8;

  for (int k0 = 0; k0 < K; k0 += 32) {
    __syncthreads();
#pragma unroll
    for (int j = 0; j < 2; ++j) {
      int c = wid * 2 + j;
      int row = c * 16 + srow;
      async_copy16(&As[c * 512], Ab + row * K + k0 + scol);
      async_copy16(&Bs[c * 512], Bb + row * K + k0 + scol);
    }
    __syncthreads();
    bf16x8 af[4], bf[4];
#pragma unroll
    for (int mt = 0; mt < 4; ++mt)
      af[mt] = *reinterpret_cast<const bf16x8*>(&As[(wm + mt * 16 + lm) * 32 + lq * 8]);
#pragma unroll
    for (int nt = 0; nt < 4; ++nt)
      bf[nt] = *reinterpret_cast<const bf16x8*>(&Bs[(wn + nt * 16 + lm) * 32 + lq * 8]);
#pragma unroll
    for (int mt = 0; mt < 4; ++mt)
#pragma unroll
      for (int nt = 0; nt < 4; ++nt)
        acc[mt][nt] = __builtin_amdgcn_mfma_f32_16x16x32_bf16(af[mt], bf[nt], acc[mt][nt], 0, 0, 0);
  }

  const float qscale = 0.18033688011112042f;  // 1/sqrt(64) * log2(e)
#pragma unroll
  for (int mt = 0; mt < 4; ++mt) {
#pragma unroll
    for (int nt = 0; nt < 4; ++nt) {
#pragma unroll
      for (int r = 0; r < 4; ++r) {
        int m = bm * 128 + wm + mt * 16 + lq * 4 + r;
        int n = bn * 128 + wn + nt * 16 + lm;
        float val = acc[mt][nt][r] + b_attn[n];
        int sel = n >> 10;
        int c = n & 1023;
        int h = c >> 6;
        int d = c & 63;
        int b = m >> 11;
        int t = m & 2047;
        if (sel == 0)      qo[(((b * NH_ + h) * T_) + t) * D_ + d] = f2bf((val + bQ[c]) * qscale);
        else if (sel == 1) ko[(((b * NH_ + h) * T_) + t) * D_ + d] = f2bf(val + bK[c]);
        else               vo[(((b * NH_ + h) * D_) + d) * T_ + t] = f2bf(val);  // transposed
      }
    }
  }
}

// ---------------- Flash attention: LDS-staged K (dbuf) + V, static vmcnt pipeline ----------------
// 1280 persistent single-wave blocks; items: qt = 63-(idx>>6) (longest first),
// bh = idx&63; steal via *ctr. All in-loop global traffic goes through
// global_load_lds (16 copies/iter); per-iteration schedule:
//   stage V_i | wait vm(8) [K_i ready] | ds_read K | S MFMA | stage K_{i+1} |
//   softmax   | wait vm(8) [V_i ready] | ds_read V | PV MFMA
// Tiles are XOR-swizzled (global-side chunk permutation) to break the
// 128B-row-stride bank aliasing; DMA LDS side stays lane-contiguous.
__global__ __launch_bounds__(64) void attn_kernel(const u16* __restrict__ q,
                                                  const u16* __restrict__ k,
                                                  const u16* __restrict__ vt,
                                                  u16* __restrict__ y,
                                                  unsigned* __restrict__ ctr) {
  int lane = threadIdx.x;
  int lm = lane & 15, lq = lane >> 4;

  __shared__ u16 Ks[2][64 * 64];   // [buf][row=key][col=d, swizzled]   16 KB
  __shared__ u16 Vs[64 * 64];      // [row=d][col=key, swizzled]         8 KB
  __shared__ u16 Ps[2][16][72];    // P relayout                        4.5 KB

  int srow = lane >> 3;            // staging: row within chunk
  int sg   = (lane & 7) ^ srow;    // swizzled col-group fetched by this lane

  int idx = blockIdx.x;
  while (idx < ATTN_ITEMS) {
    int qt = 63 - (idx >> 6);
    int bh = idx & 63;
    int b = bh >> 4, h = bh & 15;

    const u16* qb = q + ((size_t)bh * T_ + qt * 32) * D_;
    const u16* kb = k + (size_t)bh * T_ * D_;
    const u16* vb = vt + (size_t)bh * D_ * T_;   // [d][t]

    // Q as B-operand: lane n=q=lm, k=d=lq*8+j
    bf16x8 bq[2][2];
#pragma unroll
    for (int qt2 = 0; qt2 < 2; ++qt2) {
      const u16* qp = qb + (qt2 * 16 + lm) * D_ + lq * 8;
      bq[qt2][0] = *reinterpret_cast<const bf16x8*>(qp);
      bq[qt2][1] = *reinterpret_cast<const bf16x8*>(qp + 32);
    }

    f32x4 o[4][2];
#pragma unroll
    for (int dt = 0; dt < 4; ++dt)
#pragma unroll
      for (int qt2 = 0; qt2 < 2; ++qt2) o[dt][qt2] = (f32x4){0.f, 0.f, 0.f, 0.f};
    float mprev[2] = {-1e30f, -1e30f}, lsum[2] = {0.f, 0.f};

    const int klast = qt >> 1;

    // stage K tile kbi into Ks[buf]: 8 chunks x 1KB, global rows contiguous
    auto stage_K = [&](int buf, int kbi) {
      const u16* gb = kb + (size_t)(kbi * 64) * 64;
#pragma unroll
      for (int c = 0; c < 8; ++c)
        async_copy16(&Ks[buf][c * 512], gb + (c * 8 + srow) * 64 + sg * 8);
    };
    // stage V tile kbi into Vs: rows are d (global stride T_), cols key
    auto stage_V = [&](int kbi) {
      const u16* gb = vb + kbi * 64;
#pragma unroll
      for (int c = 0; c < 8; ++c)
        async_copy16(&Vs[c * 512], gb + (size_t)(c * 8 + srow) * T_ + sg * 8);
    };

    stage_K(0, 0);

    for (int kbi = 0; kbi <= klast; ++kbi) {
      int buf = kbi & 1;
      stage_V(kbi);
      WAIT_VM8();                  // K_kbi (and first-iter bq/prev stores) landed
      // K frags: row=kt*16+lm, swizzled col-group (half*4+lq)^(lm&7)
      bf16x8 kf[4][2];
#pragma unroll
      for (int kt = 0; kt < 4; ++kt) {
        const u16* base = &Ks[buf][(kt * 16 + lm) * 64];
        kf[kt][0] = *reinterpret_cast<const bf16x8*>(base + ((lq ^ (lm & 7)) * 8));
        kf[kt][1] = *reinterpret_cast<const bf16x8*>(base + (((4 + lq) ^ (lm & 7)) * 8));
      }

      // S^T[key][q] (exp2 domain: q pre-scaled)
      f32x4 s[4][2];
#pragma unroll
      for (int kt = 0; kt < 4; ++kt)
#pragma unroll
        for (int qt2 = 0; qt2 < 2; ++qt2) {
          f32x4 z = (f32x4){0.f, 0.f, 0.f, 0.f};
          z = __builtin_amdgcn_mfma_f32_16x16x32_bf16(kf[kt][0], bq[qt2][0], z, 0, 0, 0);
          z = __builtin_amdgcn_mfma_f32_16x16x32_bf16(kf[kt][1], bq[qt2][1], z, 0, 0, 0);
          s[kt][qt2] = z;
        }

      // stage next K (clamped redundant on last iter to keep vmcnt counts static)
      stage_K(buf ^ 1, (kbi + 1 <= klast) ? kbi + 1 : klast);

      bool maskt = (kbi == klast);
#pragma unroll
      for (int qt2 = 0; qt2 < 2; ++qt2) {
        int qg = qt * 32 + qt2 * 16 + lm;
        float mval = -1e30f;
        if (maskt) {
#pragma unroll
          for (int kt = 0; kt < 4; ++kt)
#pragma unroll
            for (int r = 0; r < 4; ++r) {
              int key = kbi * 64 + kt * 16 + lq * 4 + r;
              float sv = (key > qg) ? -1e30f : s[kt][qt2][r];
              s[kt][qt2][r] = sv;
              mval = fmaxf(mval, sv);
            }
        } else {
#pragma unroll
          for (int kt = 0; kt < 4; ++kt)
#pragma unroll
            for (int r = 0; r < 4; ++r) mval = fmaxf(mval, s[kt][qt2][r]);
        }
        mval = fmaxf(mval, __shfl_xor(mval, 16));
        mval = fmaxf(mval, __shfl_xor(mval, 32));
        float mold = mprev[qt2];
        float mnew = fmaxf(mold, mval);
        unsigned long long upd = __ballot(mval > mold);
        if (upd) {
          float alpha = __builtin_exp2f(mold - mnew);
          lsum[qt2] *= alpha;
#pragma unroll
          for (int dt = 0; dt < 4; ++dt) o[dt][qt2] *= alpha;
          mprev[qt2] = mnew;
        }
        float rs = 0.f;
#pragma unroll
        for (int kt = 0; kt < 4; ++kt) {
          unsigned pu[4];
#pragma unroll
          for (int r = 0; r < 4; ++r) {
            float p = __builtin_exp2f(s[kt][qt2][r] - mnew);
            rs += p;
            union { float f; unsigned u; } cc; cc.f = p;
            pu[r] = cc.u;
          }
          // truncating bf16 pack via v_perm: D = (bf16(pu0), bf16(pu1))
          unsigned w0 = __builtin_amdgcn_perm(pu[1], pu[0], 0x07060302u);
          unsigned w1 = __builtin_amdgcn_perm(pu[3], pu[2], 0x07060302u);
          unsigned long long wv = ((unsigned long long)w1 << 32) | w0;
          *reinterpret_cast<unsigned long long*>(&Ps[qt2][lm][kt * 16 + lq * 4]) = wv;
        }
        rs += __shfl_xor(rs, 16);
        rs += __shfl_xor(rs, 32);
        lsum[qt2] += rs;
      }

      WAIT_VM8();                  // V_kbi landed (next K still in flight)
      // V frags: row=dt*16+lm, swizzled col-group
      bf16x8 vf[4][2];
#pragma unroll
      for (int dt = 0; dt < 4; ++dt) {
        const u16* base = &Vs[(dt * 16 + lm) * 64];
        vf[dt][0] = *reinterpret_cast<const bf16x8*>(base + ((lq ^ (lm & 7)) * 8));
        vf[dt][1] = *reinterpret_cast<const bf16x8*>(base + (((4 + lq) ^ (lm & 7)) * 8));
      }

      // PV: O^T += V^T P^T
#pragma unroll
      for (int qt2 = 0; qt2 < 2; ++qt2) {
        bf16x8 p0 = *reinterpret_cast<const bf16x8*>(&Ps[qt2][lm][lq * 8]);
        bf16x8 p1 = *reinterpret_cast<const bf16x8*>(&Ps[qt2][lm][32 + lq * 8]);
#pragma unroll
        for (int dt = 0; dt < 4; ++dt) {
          o[dt][qt2] = __builtin_amdgcn_mfma_f32_16x16x32_bf16(vf[dt][0], p0, o[dt][qt2], 0, 0, 0);
          o[dt][qt2] = __builtin_amdgcn_mfma_f32_16x16x32_bf16(vf[dt][1], p1, o[dt][qt2], 0, 0, 0);
        }
      }
    }

    // write y[b][t=q][h][d]; O^T C-layout: col=q=lm, row=d=dt*16+lq*4+r -> 8B stores
#pragma unroll
    for (int qt2 = 0; qt2 < 2; ++qt2) {
      float inv = 1.f / lsum[qt2];
      int qg = qt * 32 + qt2 * 16 + lm;
#pragma unroll
      for (int dt = 0; dt < 4; ++dt) {
        u16 w[4];
#pragma unroll
        for (int r = 0; r < 4; ++r) w[r] = f2bf(o[dt][qt2][r] * inv);
        int d = dt * 16 + lq * 4;
        *reinterpret_cast<uint2*>(&y[((size_t)(b * T_ + qg) * NH_ + h) * D_ + d]) =
            *reinterpret_cast<uint2*>(w);
      }
    }

    unsigned nv = 0;
    if (lane == 0) nv = atomicAdd(ctr, 1u);
    idx = __shfl((int)nv, 0);
  }
}

// ---------------- Proj GEMM (R5 BK=32 m97 structure) ----------------
__global__ __launch_bounds__(256) void gemm_proj(const u16* __restrict__ A,
                                                 const u16* __restrict__ Bt,
                                                 const float* __restrict__ b_proj,
                                                 float* __restrict__ out) {
  const int K = C_, N = C_;
  int bm = blockIdx.y, bn = blockIdx.x;
  int tid = threadIdx.x;
  int wid = tid >> 6, lane = tid & 63;
  int lm = lane & 15, lq = lane >> 4;
  int wm = (wid >> 1) * 64, wn = (wid & 1) * 64;

  __shared__ u16 As[128 * 32];
  __shared__ u16 Bs[128 * 32];

  f32x4 acc[4][4];
#pragma unroll
  for (int i = 0; i < 4; ++i)
#pragma unroll
    for (int j = 0; j < 4; ++j) acc[i][j] = (f32x4){0.f, 0.f, 0.f, 0.f};

  const u16* Ab = A + (bm * 128) * K;
  const u16* Bb = Bt + (bn * 128) * K;
  int srow = lane >> 2;
  int scol = (lane & 3) * 8;

  for (int k0 = 0; k0 < K; k0 += 32) {
    __syncthreads();
#pragma unroll
    for (int j = 0; j < 2; ++j) {
      int c = wid * 2 + j;
      int row = c * 16 + srow;
      async_copy16(&As[c * 512], Ab + row * K + k0 + scol);
      async_copy16(&Bs[c * 512], Bb + row * K + k0 + scol);
    }
    __syncthreads();
    bf16x8 af[4], bf[4];
#pragma unroll
    for (int mt = 0; mt < 4; ++mt)
      af[mt] = *reinterpret_cast<const bf16x8*>(&As[(wm + mt * 16 + lm) * 32 + lq * 8]);
#pragma unroll
    for (int nt = 0; nt < 4; ++nt)
      bf[nt] = *reinterpret_cast<const bf16x8*>(&Bs[(wn + nt * 16 + lm) * 32 + lq * 8]);
#pragma unroll
    for (int mt = 0; mt < 4; ++mt)
#pragma unroll
      for (int nt = 0; nt < 4; ++nt)
        acc[mt][nt] = __builtin_amdgcn_mfma_f32_16x16x32_bf16(af[mt], bf[nt], acc[mt][nt], 0, 0, 0);
  }

#pragma unroll
  for (int mt = 0; mt < 4; ++mt) {
#pragma unroll
    for (int nt = 0; nt < 4; ++nt) {
#pragma unroll
      for (int r = 0; r < 4; ++r) {
        int m = bm * 128 + wm + mt * 16 + lq * 4 + r;
        int n = bn * 128 + wn + nt * 16 + lm;
        out[m * N + n] = acc[mt][nt][r] + b_proj[n];
      }
    }
  }
}

extern "C" void kernel_launch(void* const* d_in, const int* in_sizes, int n_in,
                              void* d_out, int out_size, void* d_ws, size_t ws_size,
                              hipStream_t stream) {
  const float* x      = (const float*)d_in[0];
  const float* W_attn = (const float*)d_in[1];
  const float* b_attn = (const float*)d_in[2];
  const float* bQ     = (const float*)d_in[3];
  const float* bK     = (const float*)d_in[4];
  const float* W_proj = (const float*)d_in[5];
  const float* b_proj = (const float*)d_in[6];
  float* out = (float*)d_out;

  char* ws = (char*)d_ws;
  u16* xb  = (u16*)(ws);                              // [8192][1024]      16 MB
  u16* WaT = (u16*)(ws + 16777216);                   // [3072][1024]       6 MB
  u16* WpT = (u16*)(ws + 23068672);                   // [1024][1024]       2 MB
  u16* qw  = (u16*)(ws + 25165824);                   // [B,NH,T,D] scaled 16 MB
  u16* kw  = (u16*)(ws + 41943040);                   // [B,NH,T,D]        16 MB
  u16* vw  = (u16*)(ws + 58720256);                   // [B,NH,D,T] (V^T)  16 MB
  u16* yw  = (u16*)(ws + 75497472);                   // [8192][1024]      16 MB
  unsigned* ctr = (unsigned*)(ws + 92274688);         // work-steal counter

  conv_bf16<<<M_ * C_ / (4 * 256), 256, 0, stream>>>(x, xb, M_ * C_);
  {
    dim3 g(N_QKV / 32, C_ / 32);
    transpose_bf16<<<g, 256, 0, stream>>>(W_attn, WaT, C_, N_QKV);
  }
  {
    dim3 g(C_ / 32, C_ / 32);
    transpose_bf16<<<g, 256, 0, stream>>>(W_proj, WpT, C_, C_);
  }
  {
    dim3 g(N_QKV / 128, M_ / 128);  // (24, 64)
    gemm_qkv<<<g, 256, 0, stream>>>(xb, WaT, b_attn, bQ, bK, qw, kw, vw, ctr);
  }
  attn_kernel<<<ATTN_WAVES, 64, 0, stream>>>(qw, kw, vw, yw, ctr);
  {
    dim3 g(C_ / 128, M_ / 128);     // (8, 64)
    gemm_proj<<<g, 256, 0, stream>>>(yw, WpT, b_proj, out);
  }
}

// Round 8
// 351.978 us; speedup vs baseline: 1.0975x; 1.0024x over previous
//
#include <hip/hip_runtime.h>

typedef unsigned short u16;
typedef unsigned int u32;
typedef __bf16 bf16x8 __attribute__((ext_vector_type(8)));
typedef float f32x4 __attribute__((ext_vector_type(4)));

#define B_  4
#define T_  2048
#define C_  1024
#define NH_ 16
#define D_  64
#define M_  (B_*T_)          // 8192
#define N_QKV (3*C_)         // 3072

#define ATTN_BLOCKS 768      // 3 blocks/CU (LDS-limited), 4 waves each
#define ATTN_ITEMS 1024      // 64 bh x 16 q-tiles of 128 rows

// raw barrier + static waitcnt (no vmcnt(0) drain -- keeps prefetch in flight)
#define BARRIER()  __asm__ __volatile__("s_barrier" ::: "memory")
#define WAIT_VM4() __asm__ __volatile__("s_waitcnt vmcnt(4)" ::: "memory")

// async global->LDS, 16B per lane. LDS dest = wave-uniform base + lane*16
__device__ __forceinline__ void async_copy16(void* lds, const void* gptr) {
  __builtin_amdgcn_global_load_lds(
      (const __attribute__((address_space(1))) u32*)gptr,
      (__attribute__((address_space(3))) u32*)(u32)(uintptr_t)lds,
      16, 0, 0);
}

// RNE float -> bf16 bits
__device__ __forceinline__ u16 f2bf(float f) {
  union { float f; unsigned u; } c; c.f = f;
  unsigned u = c.u;
  unsigned r = (u + 0x7fffu + ((u >> 16) & 1u)) >> 16;
  return (u16)r;
}

// ---------------- elementwise fp32 -> bf16 ----------------
__global__ __launch_bounds__(256) void conv_bf16(const float* __restrict__ in,
                                                 u16* __restrict__ out, int n) {
  int i = (blockIdx.x * 256 + threadIdx.x) * 4;
  if (i < n) {
    float4 f = *reinterpret_cast<const float4*>(in + i);
    u16 o[4] = { f2bf(f.x), f2bf(f.y), f2bf(f.z), f2bf(f.w) };
    *reinterpret_cast<uint2*>(out + i) = *reinterpret_cast<uint2*>(o);
  }
}

// ---------------- transpose fp32 [K][N] -> bf16 [N][K] ----------------
__global__ __launch_bounds__(256) void transpose_bf16(const float* __restrict__ in,
                                                      u16* __restrict__ out,
                                                      int K, int N) {
  __shared__ float tile[32][33];
  int bi = blockIdx.y;
  int bj = blockIdx.x;
  int tx = threadIdx.x & 31;
  int ty = threadIdx.x >> 5;
#pragma unroll
  for (int i = 0; i < 4; ++i) {
    int row = ty + i * 8;
    tile[row][tx] = in[(bi * 32 + row) * N + bj * 32 + tx];
  }
  __syncthreads();
#pragma unroll
  for (int i = 0; i < 4; ++i) {
    int row = ty + i * 8;
    out[(bj * 32 + row) * K + bi * 32 + tx] = f2bf(tile[tx][row]);
  }
}

// ---------------- QKV GEMM (R5 BK=32 m97 structure) ----------------
__global__ __launch_bounds__(256) void gemm_qkv(const u16* __restrict__ A,
                                                const u16* __restrict__ Bt,
                                                const float* __restrict__ b_attn,
                                                const float* __restrict__ bQ,
                                                const float* __restrict__ bK,
                                                u16* __restrict__ qo,
                                                u16* __restrict__ ko,
                                                u16* __restrict__ vo,
                                                unsigned* __restrict__ ctr) {
  const int K = C_;
  int bm = blockIdx.y, bn = blockIdx.x;
  int tid = threadIdx.x;
  if (tid == 0 && bm == 0 && bn == 0) *ctr = ATTN_BLOCKS;
  int wid = tid >> 6, lane = tid & 63;
  int lm = lane & 15, lq = lane >> 4;
  int wm = (wid >> 1) * 64, wn = (wid & 1) * 64;

  __shared__ u16 As[128 * 32];
  __shared__ u16 Bs[128 * 32];

  f32x4 acc[4][4];
#pragma unroll
  for (int i = 0; i < 4; ++i)
#pragma unroll
    for (int j = 0; j < 4; ++j) acc[i][j] = (f32x4){0.f, 0.f, 0.f, 0.f};

  const u16* Ab = A + (bm * 128) * K;
  const u16* Bb = Bt + (bn * 128) * K;
  int srow = lane >> 2;
  int scol = (lane & 3) * 8;

  for (int k0 = 0; k0 < K; k0 += 32) {
    __syncthreads();
#pragma unroll
    for (int j = 0; j < 2; ++j) {
      int c = wid * 2 + j;
      int row = c * 16 + srow;
      async_copy16(&As[c * 512], Ab + row * K + k0 + scol);
      async_copy16(&Bs[c * 512], Bb + row * K + k0 + scol);
    }
    __syncthreads();
    bf16x8 af[4], bf[4];
#pragma unroll
    for (int mt = 0; mt < 4; ++mt)
      af[mt] = *reinterpret_cast<const bf16x8*>(&As[(wm + mt * 16 + lm) * 32 + lq * 8]);
#pragma unroll
    for (int nt = 0; nt < 4; ++nt)
      bf[nt] = *reinterpret_cast<const bf16x8*>(&Bs[(wn + nt * 16 + lm) * 32 + lq * 8]);
#pragma unroll
    for (int mt = 0; mt < 4; ++mt)
#pragma unroll
      for (int nt = 0; nt < 4; ++nt)
        acc[mt][nt] = __builtin_amdgcn_mfma_f32_16x16x32_bf16(af[mt], bf[nt], acc[mt][nt], 0, 0, 0);
  }

  const float qscale = 0.18033688011112042f;  // 1/sqrt(64) * log2(e)
#pragma unroll
  for (int mt = 0; mt < 4; ++mt) {
#pragma unroll
    for (int nt = 0; nt < 4; ++nt) {
#pragma unroll
      for (int r = 0; r < 4; ++r) {
        int m = bm * 128 + wm + mt * 16 + lq * 4 + r;
        int n = bn * 128 + wn + nt * 16 + lm;
        float val = acc[mt][nt][r] + b_attn[n];
        int sel = n >> 10;
        int c = n & 1023;
        int h = c >> 6;
        int d = c & 63;
        int b = m >> 11;
        int t = m & 2047;
        if (sel == 0)      qo[(((b * NH_ + h) * T_) + t) * D_ + d] = f2bf((val + bQ[c]) * qscale);
        else if (sel == 1) ko[(((b * NH_ + h) * T_) + t) * D_ + d] = f2bf(val + bK[c]);
        else               vo[(((b * NH_ + h) * D_) + d) * T_ + t] = f2bf(val);  // transposed
      }
    }
  }
}

// ---------------- Flash attention: 4-wave blocks, shared K/V LDS double-buffer ----------------
// 768 persistent 256-thread blocks; item = (bh, 128-row q-tile); bh = idx>>4
// (bh-major for L2 locality), qt = 15-(idx&15) (longest first). 4 waves each own
// 32 q-rows and share DMA-staged K/V tiles (both double-buffered). Pipeline:
//   prologue: stage tiles 0,1 (4 DMA/wave each)
//   iter i:   wait vmcnt(4) [own share of tile i landed] ; s_barrier
//             S MFMA + softmax + PV MFMA from buf i&1
//             s_barrier ; stage tile i+2 into buf (clamped -> static vmcnt counts)
// No vmcnt(0) drain anywhere in the loop. Softmax identical to R7 (per-wave).
__global__ __launch_bounds__(256) void attn_kernel(const u16* __restrict__ q,
                                                   const u16* __restrict__ k,
                                                   const u16* __restrict__ vt,
                                                   u16* __restrict__ y,
                                                   unsigned* __restrict__ ctr) {
  int tid = threadIdx.x;
  int w = tid >> 6, lane = tid & 63;
  int lm = lane & 15, lq = lane >> 4;

  __shared__ u16 Ks[2][64 * 64];   // [buf][key][d swizzled]    16 KB
  __shared__ u16 Vs[2][64 * 64];   // [buf][d][key swizzled]    16 KB
  __shared__ u16 Ps[4][2][16][72]; // per-wave P relayout        18 KB
  __shared__ int nidx;

  int srow = lane >> 3;            // staging row within 8-row chunk
  int sg   = (lane & 7) ^ srow;    // swizzled 16B col-group

  int idx = blockIdx.x;
  while (idx < ATTN_ITEMS) {
    int bh = idx >> 4;
    int qt = 15 - (idx & 15);
    int b = bh >> 4, h = bh & 15;
    const int klast = 2 * qt + 1;
    const int qrow0 = qt * 128 + w * 32;

    const u16* qb = q + ((size_t)bh * T_ + qrow0) * D_;
    const u16* kb = k + (size_t)bh * T_ * D_;
    const u16* vb = vt + (size_t)bh * D_ * T_;   // [d][t]

    // wave w stages chunks {2w, 2w+1} of each 8 KB tile (2 DMA instr/tile)
    auto stage_K = [&](int buf, int kbi) {
      const u16* gb = kb + (size_t)(kbi * 64) * 64;
#pragma unroll
      for (int j = 0; j < 2; ++j) {
        int c = w * 2 + j;
        async_copy16(&Ks[buf][c * 512], gb + (c * 8 + srow) * 64 + sg * 8);
      }
    };
    auto stage_V = [&](int buf, int kbi) {
      const u16* gb = vb + kbi * 64;
#pragma unroll
      for (int j = 0; j < 2; ++j) {
        int c = w * 2 + j;
        async_copy16(&Vs[buf][c * 512], gb + (size_t)(c * 8 + srow) * T_ + sg * 8);
      }
    };

    // Q as B-operand: lane n=q=lm, k=d (pre-scaled by 1/sqrt(D)*log2e)
    bf16x8 bq[2][2];
#pragma unroll
    for (int qt2 = 0; qt2 < 2; ++qt2) {
      const u16* qp = qb + (qt2 * 16 + lm) * D_ + lq * 8;
      bq[qt2][0] = *reinterpret_cast<const bf16x8*>(qp);
      bq[qt2][1] = *reinterpret_cast<const bf16x8*>(qp + 32);
    }

    f32x4 o[4][2];
#pragma unroll
    for (int dt = 0; dt < 4; ++dt)
#pragma unroll
      for (int qt2 = 0; qt2 < 2; ++qt2) o[dt][qt2] = (f32x4){0.f, 0.f, 0.f, 0.f};
    float mprev[2] = {-1e30f, -1e30f}, lsum[2] = {0.f, 0.f};

    // prologue: tiles 0 and 1 (8 DMA per wave outstanding)
    stage_K(0, 0); stage_V(0, 0);
    stage_K(1, 1); stage_V(1, 1);

    for (int kbi = 0; kbi <= klast; ++kbi) {
      int buf = kbi & 1;
      WAIT_VM4();                  // own share of tile kbi landed (tile kbi+1 flying)
      BARRIER();                   // all waves' shares landed

      // K frags: row=key=kt*16+lm, swizzled col-group g^(lm&7)
      bf16x8 kf[4][2];
#pragma unroll
      for (int kt = 0; kt < 4; ++kt) {
        const u16* base = &Ks[buf][(kt * 16 + lm) * 64];
        kf[kt][0] = *reinterpret_cast<const bf16x8*>(base + ((lq ^ (lm & 7)) * 8));
        kf[kt][1] = *reinterpret_cast<const bf16x8*>(base + (((4 + lq) ^ (lm & 7)) * 8));
      }

      // S^T[key][q]
      f32x4 s[4][2];
#pragma unroll
      for (int kt = 0; kt < 4; ++kt)
#pragma unroll
        for (int qt2 = 0; qt2 < 2; ++qt2) {
          f32x4 z = (f32x4){0.f, 0.f, 0.f, 0.f};
          z = __builtin_amdgcn_mfma_f32_16x16x32_bf16(kf[kt][0], bq[qt2][0], z, 0, 0, 0);
          z = __builtin_amdgcn_mfma_f32_16x16x32_bf16(kf[kt][1], bq[qt2][1], z, 0, 0, 0);
          s[kt][qt2] = z;
        }

      bool maskt = (kbi * 64 + 63 > qrow0);
#pragma unroll
      for (int qt2 = 0; qt2 < 2; ++qt2) {
        int qg = qrow0 + qt2 * 16 + lm;
        float mval = -1e30f;
        if (maskt) {
#pragma unroll
          for (int kt = 0; kt < 4; ++kt)
#pragma unroll
            for (int r = 0; r < 4; ++r) {
              int key = kbi * 64 + kt * 16 + lq * 4 + r;
              float sv = (key > qg) ? -1e30f : s[kt][qt2][r];
              s[kt][qt2][r] = sv;
              mval = fmaxf(mval, sv);
            }
        } else {
#pragma unroll
          for (int kt = 0; kt < 4; ++kt)
#pragma unroll
            for (int r = 0; r < 4; ++r) mval = fmaxf(mval, s[kt][qt2][r]);
        }
        mval = fmaxf(mval, __shfl_xor(mval, 16));
        mval = fmaxf(mval, __shfl_xor(mval, 32));
        float mold = mprev[qt2];
        float mnew = fmaxf(mold, mval);
        unsigned long long upd = __ballot(mval > mold);
        if (upd) {
          float alpha = __builtin_exp2f(mold - mnew);
          lsum[qt2] *= alpha;
#pragma unroll
          for (int dt = 0; dt < 4; ++dt) o[dt][qt2] *= alpha;
          mprev[qt2] = mnew;
        }
        float rs = 0.f;
#pragma unroll
        for (int kt = 0; kt < 4; ++kt) {
          unsigned pu[4];
#pragma unroll
          for (int r = 0; r < 4; ++r) {
            float p = __builtin_exp2f(s[kt][qt2][r] - mnew);
            rs += p;
            union { float f; unsigned u; } cc; cc.f = p;
            pu[r] = cc.u;
          }
          unsigned w0 = __builtin_amdgcn_perm(pu[1], pu[0], 0x07060302u);
          unsigned w1 = __builtin_amdgcn_perm(pu[3], pu[2], 0x07060302u);
          unsigned long long wv = ((unsigned long long)w1 << 32) | w0;
          *reinterpret_cast<unsigned long long*>(&Ps[w][qt2][lm][kt * 16 + lq * 4]) = wv;
        }
        rs += __shfl_xor(rs, 16);
        rs += __shfl_xor(rs, 32);
        lsum[qt2] += rs;
      }

      // V frags: row=d=dt*16+lm, swizzled col-group
      bf16x8 vf[4][2];
#pragma unroll
      for (int dt = 0; dt < 4; ++dt) {
        const u16* base = &Vs[buf][(dt * 16 + lm) * 64];
        vf[dt][0] = *reinterpret_cast<const bf16x8*>(base + ((lq ^ (lm & 7)) * 8));
        vf[dt][1] = *reinterpret_cast<const bf16x8*>(base + (((4 + lq) ^ (lm & 7)) * 8));
      }

      // PV: O^T += V^T P^T  (Ps per-wave, no barrier needed for it)
#pragma unroll
      for (int qt2 = 0; qt2 < 2; ++qt2) {
        bf16x8 p0 = *reinterpret_cast<const bf16x8*>(&Ps[w][qt2][lm][lq * 8]);
        bf16x8 p1 = *reinterpret_cast<const bf16x8*>(&Ps[w][qt2][lm][32 + lq * 8]);
#pragma unroll
        for (int dt = 0; dt < 4; ++dt) {
          o[dt][qt2] = __builtin_amdgcn_mfma_f32_16x16x32_bf16(vf[dt][0], p0, o[dt][qt2], 0, 0, 0);
          o[dt][qt2] = __builtin_amdgcn_mfma_f32_16x16x32_bf16(vf[dt][1], p1, o[dt][qt2], 0, 0, 0);
        }
      }

      BARRIER();                   // all waves done reading buf before overwrite
      int nk = (kbi + 2 <= klast) ? kbi + 2 : klast;  // clamp: keeps counts static
      stage_K(buf, nk); stage_V(buf, nk);
    }

    // write y[b][t=q][h][d]; O^T C-layout: col=q=lm, row=d=dt*16+lq*4+r -> 8B stores
#pragma unroll
    for (int qt2 = 0; qt2 < 2; ++qt2) {
      float inv = 1.f / lsum[qt2];
      int qg = qrow0 + qt2 * 16 + lm;
#pragma unroll
      for (int dt = 0; dt < 4; ++dt) {
        u16 wb[4];
#pragma unroll
        for (int r = 0; r < 4; ++r) wb[r] = f2bf(o[dt][qt2][r] * inv);
        int d = dt * 16 + lq * 4;
        *reinterpret_cast<uint2*>(&y[((size_t)(b * T_ + qg) * NH_ + h) * D_ + d]) =
            *reinterpret_cast<uint2*>(wb);
      }
    }

    // block-level steal (full sync: drains the redundant tail prefetches too)
    __syncthreads();
    if (tid == 0) nidx = (int)atomicAdd(ctr, 1u);
    __syncthreads();
    idx = nidx;
  }
}

// ---------------- Proj GEMM (R5 BK=32 m97 structure) ----------------
__global__ __launch_bounds__(256) void gemm_proj(const u16* __restrict__ A,
                                                 const u16* __restrict__ Bt,
                                                 const float* __restrict__ b_proj,
                                                 float* __restrict__ out) {
  const int K = C_, N = C_;
  int bm = blockIdx.y, bn = blockIdx.x;
  int tid = threadIdx.x;
  int wid = tid >> 6, lane = tid & 63;
  int lm = lane & 15, lq = lane >> 4;
  int wm = (wid >> 1) * 64, wn = (wid & 1) * 64;

  __shared__ u16 As[128 * 32];
  __shared__ u16 Bs[128 * 32];

  f32x4 acc[4][4];
#pragma unroll
  for (int i = 0; i < 4; ++i)
#pragma unroll
    for (int j = 0; j < 4; ++j) acc[i][j] = (f32x4){0.f, 0.f, 0.f, 0.f};

  const u16* Ab = A + (bm * 128) * K;
  const u16* Bb = Bt + (bn * 128) * K;
  int srow = lane >> 2;
  int scol = (lane & 3) * 8;

  for (int k0 = 0; k0 < K; k0 += 32) {
    __syncthreads();
#pragma unroll
    for (int j = 0; j < 2; ++j) {
      int c = wid * 2 + j;
      int row = c * 16 + srow;
      async_copy16(&As[c * 512], Ab + row * K + k0 + scol);
      async_copy16(&Bs[c * 512], Bb + row * K + k0 + scol);
    }
    __syncthreads();
    bf16x8 af[4], bf[4];
#pragma unroll
    for (int mt = 0; mt < 4; ++mt)
      af[mt] = *reinterpret_cast<const bf16x8*>(&As[(wm + mt * 16 + lm) * 32 + lq * 8]);
#pragma unroll
    for (int nt = 0; nt < 4; ++nt)
      bf[nt] = *reinterpret_cast<const bf16x8*>(&Bs[(wn + nt * 16 + lm) * 32 + lq * 8]);
#pragma unroll
    for (int mt = 0; mt < 4; ++mt)
#pragma unroll
      for (int nt = 0; nt < 4; ++nt)
        acc[mt][nt] = __builtin_amdgcn_mfma_f32_16x16x32_bf16(af[mt], bf[nt], acc[mt][nt], 0, 0, 0);
  }

#pragma unroll
  for (int mt = 0; mt < 4; ++mt) {
#pragma unroll
    for (int nt = 0; nt < 4; ++nt) {
#pragma unroll
      for (int r = 0; r < 4; ++r) {
        int m = bm * 128 + wm + mt * 16 + lq * 4 + r;
        int n = bn * 128 + wn + nt * 16 + lm;
        out[m * N + n] = acc[mt][nt][r] + b_proj[n];
      }
    }
  }
}

extern "C" void kernel_launch(void* const* d_in, const int* in_sizes, int n_in,
                              void* d_out, int out_size, void* d_ws, size_t ws_size,
                              hipStream_t stream) {
  const float* x      = (const float*)d_in[0];
  const float* W_attn = (const float*)d_in[1];
  const float* b_attn = (const float*)d_in[2];
  const float* bQ     = (const float*)d_in[3];
  const float* bK     = (const float*)d_in[4];
  const float* W_proj = (const float*)d_in[5];
  const float* b_proj = (const float*)d_in[6];
  float* out = (float*)d_out;

  char* ws = (char*)d_ws;
  u16* xb  = (u16*)(ws);                              // [8192][1024]      16 MB
  u16* WaT = (u16*)(ws + 16777216);                   // [3072][1024]       6 MB
  u16* WpT = (u16*)(ws + 23068672);                   // [1024][1024]       2 MB
  u16* qw  = (u16*)(ws + 25165824);                   // [B,NH,T,D] scaled 16 MB
  u16* kw  = (u16*)(ws + 41943040);                   // [B,NH,T,D]        16 MB
  u16* vw  = (u16*)(ws + 58720256);                   // [B,NH,D,T] (V^T)  16 MB
  u16* yw  = (u16*)(ws + 75497472);                   // [8192][1024]      16 MB
  unsigned* ctr = (unsigned*)(ws + 92274688);         // work-steal counter

  conv_bf16<<<M_ * C_ / (4 * 256), 256, 0, stream>>>(x, xb, M_ * C_);
  {
    dim3 g(N_QKV / 32, C_ / 32);
    transpose_bf16<<<g, 256, 0, stream>>>(W_attn, WaT, C_, N_QKV);
  }
  {
    dim3 g(C_ / 32, C_ / 32);
    transpose_bf16<<<g, 256, 0, stream>>>(W_proj, WpT, C_, C_);
  }
  {
    dim3 g(N_QKV / 128, M_ / 128);  // (24, 64)
    gemm_qkv<<<g, 256, 0, stream>>>(xb, WaT, b_attn, bQ, bK, qw, kw, vw, ctr);
  }
  attn_kernel<<<ATTN_BLOCKS, 256, 0, stream>>>(qw, kw, vw, yw, ctr);
  {
    dim3 g(C_ / 128, M_ / 128);     // (8, 64)
    gemm_proj<<<g, 256, 0, stream>>>(yw, WpT, b_proj, out);
  }
}